// Round 11
// baseline (239.216 us; speedup 1.0000x reference)
//
#include <hip/hip_runtime.h>
#include <hip/hip_bf16.h>

// Pipeline (no global atomics — they write through to HBM per-op on MI355X;
// rounds 3/4). Build kernels need >=256 blocks and multi-block scans
// (rounds 5/7). Round 11: t is pre-scaled by dinv[src] in the dual-GEMM
// epilogue (kills the per-edge dinv load); gather is eighth-wave per edge
// (8 lanes x 16B row slice, 16 edges in flight, pure-add inner loop).

#define NCHUNK 32     // edge chunks
#define NRANGE_H 4    // hist node ranges (range = 12500)
#define HIST_H 12544
#define NRANGE_B 8    // bin2 node ranges (range = 6250; needs 2 LDS arrays)
#define HIST_B 6272

// ---------- partial histograms: a=0 deg over row, a=1 indeg over col ----------
__global__ __launch_bounds__(1024) void k_hist(const int* __restrict__ ei,
                                               int* __restrict__ partial,
                                               int N, int E, int range) {
  __shared__ int hist[HIST_H];
  int c = blockIdx.x % NCHUNK;
  int r = (blockIdx.x / NCHUNK) % NRANGE_H;
  int a = blockIdx.x / (NCHUNK * NRANGE_H);
  const int* ids = ei + (size_t)a * E;
  int lo = r * range;
  int hi = min(N, lo + range);
  int len = hi - lo;
  for (int i = threadIdx.x; i < len; i += 1024) hist[i] = 0;
  __syncthreads();
  int e0 = (int)((long long)E * c / NCHUNK);
  int e1 = (int)((long long)E * (c + 1) / NCHUNK);
  for (int e = e0 + threadIdx.x; e < e1; e += 1024) {
    int id = ids[e];
    if (id >= lo && id < hi) atomicAdd(&hist[id - lo], 1);  // LDS atomic
  }
  __syncthreads();
  int* dst = partial + ((size_t)a * NCHUNK + c) * N + lo;
  for (int i = threadIdx.x; i < len; i += 1024) dst[i] = hist[i];
}

// ---------- fused: reduce partials -> dinv/indeg, then in-block exscan ----------
__global__ __launch_bounds__(1024) void k_dinv_scan(const int* __restrict__ partial,
                                                    float* __restrict__ dinv,
                                                    int* __restrict__ indeg,
                                                    int* __restrict__ ptr,
                                                    int* __restrict__ bsum, int N) {
  __shared__ int s[1024];
  int g = blockIdx.x * 1024 + threadIdx.x;
  int deg = 0, ind = 0;
  if (g < N) {
#pragma unroll
    for (int c = 0; c < NCHUNK; ++c) {
      deg += partial[(size_t)c * N + g];
      ind += partial[((size_t)NCHUNK + c) * N + g];
    }
    dinv[g] = (deg > 0) ? (1.0f / sqrtf((float)deg)) : 0.0f;
    indeg[g] = ind;
  }
  s[threadIdx.x] = ind;
  __syncthreads();
  for (int off = 1; off < 1024; off <<= 1) {
    int tv = (threadIdx.x >= off) ? s[threadIdx.x - off] : 0;
    __syncthreads();
    s[threadIdx.x] += tv;
    __syncthreads();
  }
  if (g < N) ptr[g] = s[threadIdx.x] - ind;  // exclusive within block
  if (threadIdx.x == 1023) bsum[blockIdx.x] = s[1023];
}

// ---------- fused: scan bsum (in LDS) + finalize ptr + emit bases ----------
__global__ __launch_bounds__(256) void k_base(const int* __restrict__ partial,
                                              const int* __restrict__ bsum,
                                              int* __restrict__ ptr,
                                              int* __restrict__ base, int N, int nb) {
  __shared__ int pbs[64];
  if (threadIdx.x == 0) {
    int acc = 0;
    for (int i = 0; i < nb; ++i) { pbs[i] = acc; acc += bsum[i]; }
  }
  __syncthreads();
  int n = blockIdx.x * 256 + threadIdx.x;
  if (n >= N) return;
  int run = ptr[n] + pbs[n >> 10];
  ptr[n] = run;                      // final global exclusive scan
#pragma unroll
  for (int c = 0; c < NCHUNK; ++c) {
    base[(size_t)c * N + n] = run;
    run += partial[((size_t)NCHUNK + c) * N + n];
  }
}

// ---------- counting-sort binning (LDS atomics; base slice preloaded) ----------
__global__ __launch_bounds__(1024) void k_bin2(const int* __restrict__ ei,
                                               const int* __restrict__ base,
                                               int* __restrict__ csr_row,
                                               int N, int E, int range) {
  __shared__ int cnt[HIST_B];
  __shared__ int base_s[HIST_B];
  int c = blockIdx.x % NCHUNK;
  int r = blockIdx.x / NCHUNK;
  const int* row = ei;
  const int* col = ei + E;
  int lo = r * range;
  int hi = min(N, lo + range);
  int len = hi - lo;
  const int* bsrc = base + (size_t)c * N + lo;
  for (int i = threadIdx.x; i < len; i += 1024) {
    cnt[i] = 0;
    base_s[i] = bsrc[i];
  }
  __syncthreads();
  int e0 = (int)((long long)E * c / NCHUNK);
  int e1 = (int)((long long)E * (c + 1) / NCHUNK);
  for (int e = e0 + threadIdx.x; e < e1; e += 1024) {
    int cl = col[e];
    int rw = row[e];
    if (cl >= lo && cl < hi) {
      int off = atomicAdd(&cnt[cl - lo], 1);   // LDS atomic
      csr_row[base_s[cl - lo] + off] = rw;     // plain store (L2-absorbed)
    }
  }
}

// ---------- dual GEMM: t = (h@Wn)*dinv[row] (bf16), agg = h@Wi + bias ----------
// h and agg may ALIAS (in-place layer 2): block owns rows [64b,64b+64),
// stages each 32-row group into LDS before overwriting it; groups disjoint.
template <bool RELU>
__global__ __launch_bounds__(256) void k_dual_gemm(
    const float* h,
    const float* __restrict__ Wn,
    const float* __restrict__ Wi,
    const float* __restrict__ bias,
    const float* __restrict__ dinv,
    __hip_bfloat16* __restrict__ t, float* agg, int N) {
  __shared__ float Wn_s[64 * 64];
  __shared__ float Wi_s[64 * 64];
  __shared__ float b_s[64];
  __shared__ float h_s[32 * 68];   // 32 rows, stride 68 (pad kills store conflicts)

  const int tid = threadIdx.x;
  {
    const float4* Wn4 = (const float4*)Wn;
    const float4* Wi4 = (const float4*)Wi;
    for (int i = tid; i < 1024; i += 256) {
      ((float4*)Wn_s)[i] = Wn4[i];
      ((float4*)Wi_s)[i] = Wi4[i];
    }
  }
  if (tid < 64) b_s[tid] = bias[tid];

  const int j = tid & 63;      // output column
  const int rg = tid >> 6;     // row group 0..3 -> rows rg*8..rg*8+7
  const int r0 = blockIdx.x * 64;

  for (int g = 0; g < 2; ++g) {
    __syncthreads();  // protect h_s from prior readers; fences W staging (g=0)
    for (int v = tid; v < 512; v += 256) {
      int rr = v >> 4;
      int c4 = v & 15;
      int rload = r0 + g * 32 + rr;
      float4 val = make_float4(0.f, 0.f, 0.f, 0.f);
      if (rload < N) {
        val = *(const float4*)&h[(size_t)rload * 64 + c4 * 4];
        if (RELU) {
          val.x = fmaxf(val.x, 0.f); val.y = fmaxf(val.y, 0.f);
          val.z = fmaxf(val.z, 0.f); val.w = fmaxf(val.w, 0.f);
        }
      }
      *(float4*)&h_s[rr * 68 + c4 * 4] = val;
    }
    __syncthreads();

    float acc_t[8] = {0.f, 0.f, 0.f, 0.f, 0.f, 0.f, 0.f, 0.f};
    float acc_a[8] = {0.f, 0.f, 0.f, 0.f, 0.f, 0.f, 0.f, 0.f};
    for (int k4 = 0; k4 < 16; ++k4) {
      float4 hv[8];
#pragma unroll
      for (int r = 0; r < 8; ++r)
        hv[r] = *(const float4*)&h_s[(rg * 8 + r) * 68 + k4 * 4];
#pragma unroll
      for (int kk = 0; kk < 4; ++kk) {
        int k = k4 * 4 + kk;
        float wn = Wn_s[k * 64 + j];
        float wi = Wi_s[k * 64 + j];
#pragma unroll
        for (int r = 0; r < 8; ++r) {
          float hk = ((const float*)&hv[r])[kk];
          acc_t[r] = fmaf(hk, wn, acc_t[r]);
          acc_a[r] = fmaf(hk, wi, acc_a[r]);
        }
      }
    }
#pragma unroll
    for (int r = 0; r < 8; ++r) {
      int rr = r0 + g * 32 + rg * 8 + r;
      if (rr < N) {
        t[(size_t)rr * 64 + j] = __float2bfloat16(acc_t[r] * dinv[rr]);
        agg[(size_t)rr * 64 + j] = acc_a[r] + b_s[j];
      }
    }
  }
}

// ---------- eighth-wave CSR gather core ----------
// lane = o*8 + fl: o = edge slot (0..7), fl = feature oct (8 bf16 = 16B).
// t is pre-scaled by dinv[src]; inner loop is pure adds; dn applied once.
// Returns the reduced row in acc[0..7] (all lanes hold it after 3 shfl steps).
__device__ __forceinline__ void gather_core(
    const int* __restrict__ csr_row, const __hip_bfloat16* __restrict__ t,
    int i0, int end, int o, int fl, float* acc) {
#pragma unroll
  for (int k = 0; k < 8; ++k) acc[k] = 0.f;
  int i = i0 + o;
  for (; i + 8 < end; i += 16) {   // 16 edges in flight (2 per slot)
    int ra = csr_row[i];
    int rb = csr_row[i + 8];
    uint4 ua = *(const uint4*)&t[(size_t)ra * 64 + 8 * fl];
    uint4 ub = *(const uint4*)&t[(size_t)rb * 64 + 8 * fl];
    float va[8], vb[8];
    ((unsigned*)va)[0] = ua.x << 16; ((unsigned*)va)[1] = ua.x & 0xFFFF0000u;
    ((unsigned*)va)[2] = ua.y << 16; ((unsigned*)va)[3] = ua.y & 0xFFFF0000u;
    ((unsigned*)va)[4] = ua.z << 16; ((unsigned*)va)[5] = ua.z & 0xFFFF0000u;
    ((unsigned*)va)[6] = ua.w << 16; ((unsigned*)va)[7] = ua.w & 0xFFFF0000u;
    ((unsigned*)vb)[0] = ub.x << 16; ((unsigned*)vb)[1] = ub.x & 0xFFFF0000u;
    ((unsigned*)vb)[2] = ub.y << 16; ((unsigned*)vb)[3] = ub.y & 0xFFFF0000u;
    ((unsigned*)vb)[4] = ub.z << 16; ((unsigned*)vb)[5] = ub.z & 0xFFFF0000u;
    ((unsigned*)vb)[6] = ub.w << 16; ((unsigned*)vb)[7] = ub.w & 0xFFFF0000u;
#pragma unroll
    for (int k = 0; k < 8; ++k) acc[k] += va[k] + vb[k];
  }
  for (; i < end; i += 8) {
    int ra = csr_row[i];
    uint4 ua = *(const uint4*)&t[(size_t)ra * 64 + 8 * fl];
    float va[8];
    ((unsigned*)va)[0] = ua.x << 16; ((unsigned*)va)[1] = ua.x & 0xFFFF0000u;
    ((unsigned*)va)[2] = ua.y << 16; ((unsigned*)va)[3] = ua.y & 0xFFFF0000u;
    ((unsigned*)va)[4] = ua.z << 16; ((unsigned*)va)[5] = ua.z & 0xFFFF0000u;
    ((unsigned*)va)[6] = ua.w << 16; ((unsigned*)va)[7] = ua.w & 0xFFFF0000u;
#pragma unroll
    for (int k = 0; k < 8; ++k) acc[k] += va[k];
  }
  // reduce across the 8 edge slots
#pragma unroll
  for (int s = 8; s <= 32; s <<= 1) {
#pragma unroll
    for (int k = 0; k < 8; ++k) acc[k] += __shfl_xor(acc[k], s);
  }
}

// ---------- CSR gather (layer 1): agg[n] += dinv[n] * sum_e t'[row_e] ----------
__global__ __launch_bounds__(256) void k_gather(
    const int* __restrict__ csr_row, const int* __restrict__ ptr,
    const int* __restrict__ indeg, const float* __restrict__ dinv,
    const __hip_bfloat16* __restrict__ t, float* __restrict__ agg, int N) {
  int n = blockIdx.x * 4 + (threadIdx.x >> 6);
  if (n >= N) return;
  int lane = threadIdx.x & 63;
  int o = lane >> 3;
  int fl = lane & 7;
  int i0 = ptr[n];
  int end = i0 + indeg[n];
  float dn = dinv[n];

  float acc[8];
  gather_core(csr_row, t, i0, end, o, fl, acc);

  if (o == 0) {  // 8 lanes x 32B = full 256B fp32 row
    float4 a0 = *(const float4*)&agg[(size_t)n * 64 + 8 * fl];
    float4 a1 = *(const float4*)&agg[(size_t)n * 64 + 8 * fl + 4];
    a0.x += dn * acc[0]; a0.y += dn * acc[1]; a0.z += dn * acc[2]; a0.w += dn * acc[3];
    a1.x += dn * acc[4]; a1.y += dn * acc[5]; a1.z += dn * acc[6]; a1.w += dn * acc[7];
    *(float4*)&agg[(size_t)n * 64 + 8 * fl] = a0;
    *(float4*)&agg[(size_t)n * 64 + 8 * fl + 4] = a1;
  }
}

// ---------- FUSED layer-2 gather + output GEMM ----------
__global__ __launch_bounds__(256) void k_gather_out(
    const int* __restrict__ csr_row, const int* __restrict__ ptr,
    const int* __restrict__ indeg, const float* __restrict__ dinv,
    const __hip_bfloat16* __restrict__ t, const float* __restrict__ agg,
    const float* __restrict__ Wo,   // [64,32]
    const float* __restrict__ bo,   // [32]
    float* __restrict__ out, int N) {
  __shared__ float Wo_s[64 * 32];
  __shared__ float bo_s[32];
  __shared__ float rowbuf[4][64];

  const int tid = threadIdx.x;
  for (int i = tid; i < 2048; i += 256) Wo_s[i] = Wo[i];
  if (tid < 32) bo_s[tid] = bo[tid];
  __syncthreads();   // barrier BEFORE any divergent exit

  int w = tid >> 6;                 // wave id 0..3
  int n = blockIdx.x * 4 + w;
  if (n >= N) return;
  int lane = tid & 63;
  int o = lane >> 3;
  int fl = lane & 7;
  int i0 = ptr[n];
  int end = i0 + indeg[n];
  float dn = dinv[n];

  float acc[8];
  gather_core(csr_row, t, i0, end, o, fl, acc);

  if (o == 0) {
    float4 a0 = *(const float4*)&agg[(size_t)n * 64 + 8 * fl];
    float4 a1 = *(const float4*)&agg[(size_t)n * 64 + 8 * fl + 4];
    rowbuf[w][8 * fl + 0] = fmaxf(a0.x + dn * acc[0], 0.f);
    rowbuf[w][8 * fl + 1] = fmaxf(a0.y + dn * acc[1], 0.f);
    rowbuf[w][8 * fl + 2] = fmaxf(a0.z + dn * acc[2], 0.f);
    rowbuf[w][8 * fl + 3] = fmaxf(a0.w + dn * acc[3], 0.f);
    rowbuf[w][8 * fl + 4] = fmaxf(a1.x + dn * acc[4], 0.f);
    rowbuf[w][8 * fl + 5] = fmaxf(a1.y + dn * acc[5], 0.f);
    rowbuf[w][8 * fl + 6] = fmaxf(a1.z + dn * acc[6], 0.f);
    rowbuf[w][8 * fl + 7] = fmaxf(a1.w + dn * acc[7], 0.f);
  }
  // same-wave LDS RAW: compiler inserts lgkmcnt wait; no barrier needed.
  int half = lane >> 5;      // k-range half
  int j = lane & 31;         // output column
  float ov = 0.f;
#pragma unroll 8
  for (int k = 32 * half; k < 32 * half + 32; ++k)
    ov = fmaf(rowbuf[w][k], Wo_s[k * 32 + j], ov);
  ov += __shfl_xor(ov, 32);
  if (half == 0) out[(size_t)n * 32 + j] = ov + bo_s[j];
}

extern "C" void kernel_launch(void* const* d_in, const int* in_sizes, int n_in,
                              void* d_out, int out_size, void* d_ws, size_t ws_size,
                              hipStream_t stream) {
  const float* x = (const float*)d_in[0];
  const int* ei = (const int*)d_in[1];
  const float* W_in1 = (const float*)d_in[2];
  const float* W_neigh1 = (const float*)d_in[3];
  const float* bias1 = (const float*)d_in[4];
  const float* W_in2 = (const float*)d_in[5];
  const float* W_neigh2 = (const float*)d_in[6];
  const float* bias2 = (const float*)d_in[7];
  const float* W_out = (const float*)d_in[8];
  const float* b_out = (const float*)d_in[9];
  float* out = (float*)d_out;

  const int N = in_sizes[0] / 64;
  const int E = in_sizes[1] / 2;

  char* ws = (char*)d_ws;
  size_t off = 0;
  auto alloc = [&](size_t bytes) -> void* {
    void* p = ws + off;
    off += (bytes + 255) & ~(size_t)255;
    return p;
  };
  float* dinv = (float*)alloc((size_t)N * 4);
  int* indeg = (int*)alloc((size_t)N * 4);
  int* ptr = (int*)alloc((size_t)N * 4);
  int* bsum = (int*)alloc(256);
  int* csr_row = (int*)alloc((size_t)E * 4);
  int* partial = (int*)alloc((size_t)2 * NCHUNK * N * 4);
  int* base = (int*)alloc((size_t)NCHUNK * N * 4);
  __hip_bfloat16* t = (__hip_bfloat16*)alloc((size_t)N * 64 * 2);
  float* agg = (float*)alloc((size_t)N * 64 * 4);
  (void)ws_size;

  int range_h = (N + NRANGE_H - 1) / NRANGE_H;  // 12500 <= HIST_H
  int range_b = (N + NRANGE_B - 1) / NRANGE_B;  // 6250  <= HIST_B
  int gN = (N + 255) / 256;
  int gRows = (N + 63) / 64;
  int gNode = (N + 3) / 4;
  int nb = (N + 1023) / 1024;

  k_hist<<<2 * NRANGE_H * NCHUNK, 1024, 0, stream>>>(ei, partial, N, E, range_h);
  k_dinv_scan<<<nb, 1024, 0, stream>>>(partial, dinv, indeg, ptr, bsum, N);
  k_base<<<gN, 256, 0, stream>>>(partial, bsum, ptr, base, N, nb);
  k_bin2<<<NRANGE_B * NCHUNK, 1024, 0, stream>>>(ei, base, csr_row, N, E, range_b);

  // layer 1
  k_dual_gemm<false><<<gRows, 256, 0, stream>>>(x, W_neigh1, W_in1, bias1, dinv, t, agg, N);
  k_gather<<<gNode, 256, 0, stream>>>(csr_row, ptr, indeg, dinv, t, agg, N);

  // layer 2 (in-place on agg), then fused gather+output
  k_dual_gemm<true><<<gRows, 256, 0, stream>>>(agg, W_neigh2, W_in2, bias2, dinv, t, agg, N);
  k_gather_out<<<gNode, 256, 0, stream>>>(csr_row, ptr, indeg, dinv, t, agg,
                                          W_out, b_out, out, N);
}